// Round 13
// baseline (474.852 us; speedup 1.0000x reference)
//
#include <hip/hip_runtime.h>
#include <math.h>

// ---- problem constants ----
#define Dm   512
#define Nn_  256
#define Bv   2
#define NTD  1024          // dedup rows: (group g, batch bb, pos nn)
#define NH   8
#define DH   64
#define DFF  1365
#define DFF2 2730
#define KFF  1408
#define NFF  2816
#define NMD  14            // max distinct pooled-context entries
#define EPSR 1.1920929e-07f

typedef _Float16 h16;
typedef h16  v8h  __attribute__((ext_vector_type(8)));
typedef float v4f __attribute__((ext_vector_type(4)));

__device__ inline h16 f2h(float v) { return (h16)v; }

__device__ inline void glds16(const void* g, void* l) {
    __builtin_amdgcn_global_load_lds((const __attribute__((address_space(1))) void*)g,
                                     (__attribute__((address_space(3))) void*)l, 16, 0, 0);
}

// =====================================================================
// Multi-GEMM dispatcher (4 descriptors), fp16 3-term compensated,
// double-buffered LDS, templated tile BM x BN (BN in {64,128}).
// Optional per-row scale rss (folded RMSNorm) applied before bias.
// modes: 0 fp32 C; 1 fp16 hi/lo Cbf; 2 both; 3 pooled-ctx remap
// (md = mbase*2 + group); 4 attn KV split; 5 final 3-copy expand;
// 6 fused GLU-GELU: paired cols (sim,gate) -> sim*gelu(gate) -> Cbf.
// =====================================================================
struct GDesc {
    const h16* A;
    const h16* W;
    const float* bias;
    const float* rss;
    float* C;
    h16* Cbf;
    long Apl, Wpl, bfpl;
    int lda, ldw, ldc, Nd, mbase, K, mode, nbx;
};

template <int BM, int BN>
__global__ __launch_bounds__(256) void mega_gemm(GDesc d0, GDesc d1, GDesc d2, GDesc d3,
                                                 int n0, int n01, int n012)
{
    constexpr int NWN = (BN == 128) ? 2 : 1;   // n-dir waves
    constexpr int NWM = 4 / NWN;               // m-dir waves
    constexpr int MI = BM / (16 * NWM);        // 16-row tiles per wave
    constexpr int ABUF = BM * 32;
    constexpr int WBUFh = BN * 32;
    constexpr int BUF = 2 * ABUF + 2 * WBUFh;
    constexpr int ASEG = BM / 16;
    constexpr int WSEG = BN / 16;
    constexpr int NSEG = 2 * ASEG + 2 * WSEG;
    __shared__ h16 lds[2 * BUF];

    GDesc d; int lb = blockIdx.x;
    if (lb < n0) d = d0;
    else if (lb < n01) { d = d1; lb -= n0; }
    else if (lb < n012) { d = d2; lb -= n01; }
    else { d = d3; lb -= n012; }
    const int bx = lb % d.nbx;
    const int by = lb / d.nbx;

    const int tid = threadIdx.x;
    const int wid = tid >> 6;
    const int lane = tid & 63;
    const int wm = wid / NWN, wn = wid % NWN;
    const int row16 = lane & 15, quad = lane >> 4;
    const long i0 = (long)bx * BM;
    const long j0 = (long)by * BN;
    const int l4 = lane >> 2;
    const int l2s = ((lane & 3) ^ (l4 & 3)) * 8;
    const int ksw = (quad ^ (row16 & 3)) * 8;

    auto stage = [&](int k0, h16* buf) {
        #pragma unroll
        for (int s = 0; s < NSEG / 4; ++s) {
            const int sg = wid * (NSEG / 4) + s;
            const h16* src;
            int dst;
            if (sg < ASEG) {
                src = d.A + (i0 + sg * 16 + l4) * (long)d.lda + k0 + l2s;
                dst = sg * 512;
            } else if (sg < 2 * ASEG) {
                const int r = sg - ASEG;
                src = d.A + d.Apl + (i0 + r * 16 + l4) * (long)d.lda + k0 + l2s;
                dst = ABUF + r * 512;
            } else if (sg < 2 * ASEG + WSEG) {
                const int r = sg - 2 * ASEG;
                src = d.W + (j0 + r * 16 + l4) * (long)d.ldw + k0 + l2s;
                dst = 2 * ABUF + r * 512;
            } else {
                const int r = sg - 2 * ASEG - WSEG;
                src = d.W + d.Wpl + (j0 + r * 16 + l4) * (long)d.ldw + k0 + l2s;
                dst = 2 * ABUF + WBUFh + r * 512;
            }
            glds16(src, &buf[dst]);
        }
    };

    v4f acc[MI][4];
    #pragma unroll
    for (int a = 0; a < MI; ++a)
        #pragma unroll
        for (int b = 0; b < 4; ++b) acc[a][b] = (v4f){0.f, 0.f, 0.f, 0.f};

    stage(0, lds);
    int cur = 0;
    for (int k0 = 0; k0 < d.K; k0 += 32) {
        __syncthreads();
        h16* cbuf = &lds[cur * BUF];
        if (k0 + 32 < d.K) stage(k0 + 32, &lds[(cur ^ 1) * BUF]);

        v8h af[MI], al[MI];
        #pragma unroll
        for (int mi = 0; mi < MI; ++mi) {
            const int aoff = (wm * (16 * MI) + mi * 16 + row16) * 32 + ksw;
            af[mi] = *(const v8h*)&cbuf[aoff];
            al[mi] = *(const v8h*)&cbuf[ABUF + aoff];
        }
        #pragma unroll
        for (int nj = 0; nj < 4; ++nj) {
            const int boff = (wn * 64 + nj * 16 + row16) * 32 + ksw;
            v8h bh = *(const v8h*)&cbuf[2 * ABUF + boff];
            v8h bl = *(const v8h*)&cbuf[2 * ABUF + WBUFh + boff];
            #pragma unroll
            for (int mi = 0; mi < MI; ++mi) {
                acc[mi][nj] = __builtin_amdgcn_mfma_f32_16x16x32_f16(af[mi], bh, acc[mi][nj], 0, 0, 0);
                acc[mi][nj] = __builtin_amdgcn_mfma_f32_16x16x32_f16(af[mi], bl, acc[mi][nj], 0, 0, 0);
                acc[mi][nj] = __builtin_amdgcn_mfma_f32_16x16x32_f16(al[mi], bh, acc[mi][nj], 0, 0, 0);
            }
        }
        cur ^= 1;
    }

    #pragma unroll
    for (int nj = 0; nj < 4; ++nj) {
        const int col = (int)j0 + wn * 64 + nj * 16 + row16;
        if (col < d.Nd) {
            const float bv = d.bias ? d.bias[col] : 0.f;
            #pragma unroll
            for (int mi = 0; mi < MI; ++mi) {
                #pragma unroll
                for (int r = 0; r < 4; ++r) {
                    const long row = i0 + wm * (16 * MI) + mi * 16 + quad * 4 + r;
                    float v = acc[mi][nj][r];
                    if (d.rss) v *= d.rss[(int)row];
                    v += bv;
                    if (d.mode == 0) {
                        d.C[row * (long)d.ldc + col] = v;
                    } else if (d.mode == 1) {
                        const long idx = row * (long)d.ldc + col;
                        const h16 hi = f2h(v);
                        d.Cbf[idx] = hi; d.Cbf[idx + d.bfpl] = f2h(v - (float)hi);
                    } else if (d.mode == 2) {
                        const long idx = row * (long)d.ldc + col;
                        d.C[idx] = v;
                        const h16 hi = f2h(v);
                        d.Cbf[idx] = hi; d.Cbf[idx + d.bfpl] = f2h(v - (float)hi);
                    } else if (d.mode == 3) {
                        const int rr = (int)row & 1023;
                        const int md = d.mbase * 2 + (rr >> 9);
                        const long orow = (long)(((rr >> 8) & 1) * 256 + (rr & 255)) * NMD + md;
                        d.C[orow * 1024 + col] = v;
                    } else if (d.mode == 4) {
                        const h16 hi = f2h(v);
                        const h16 lo = f2h(v - (float)hi);
                        if (col < 512) {
                            const long idx = row * 512 + col;
                            d.Cbf[idx] = hi; d.Cbf[idx + d.bfpl] = lo;
                        } else {
                            const int c = col - 512;
                            const int bh_ = ((int)(row >> 8)) * 8 + (c >> 6);
                            const long idx = (((long)bh_ * 64 + (c & 63)) << 8) + (row & 255);
                            h16* vtp = (h16*)d.C;
                            vtp[idx] = hi; vtp[idx + d.bfpl] = lo;
                        }
                    } else if (d.mode == 5) {
                        const int g = (int)(row >> 9), bb = ((int)row >> 8) & 1, nn = (int)row & 255;
                        #pragma unroll
                        for (int rep = 0; rep < 3; ++rep) {
                            const long orow = (long)(((g * 3 + rep) * 2 + bb) * 256 + nn);
                            d.C[orow * (long)d.ldc + col] = v;
                        }
                    } else {
                        // mode 6: paired (sim,gate) cols; even lane writes
                        // sim * gelu(gate) to Cbf[row][col>>1] hi/lo.
                        // Partner lane (col^1) is always active when this
                        // lane's even col < Nd (Nd even).
                        const float gt = __shfl_xor(v, 1, 64);
                        if ((col & 1) == 0) {
                            const float ge = 0.5f * gt * (1.f + erff(gt * 0.70710678118654752440f));
                            const float out = v * ge;
                            const long idx = row * (long)d.ldc + (col >> 1);
                            const h16 hi = f2h(out);
                            d.Cbf[idx] = hi; d.Cbf[idx + d.bfpl] = f2h(out - (float)hi);
                        }
                    }
                }
            }
        }
    }
}

// =====================================================================
// Fused setup: weight converts (+norm folds, pair-interleave, transposes),
// bias folds, token replicate. One dispatch, compile-time block ranges.
// =====================================================================
struct SetupP {
    const float *attn_wq, *attn_wkv, *ff_keys_w, *ff_keys_b, *res_wq, *res_wkv,
                *res_wo, *attn_wo, *ff_values_w, *ff_values_b,
                *attn_norm_w, *ff_norm_w, *res_norm_w, *tok_in;
    h16 *wqb, *wkvb, *fkb, *rqb, *rkvb, *rob, *woTb, *fvwTb, *tokbf;
    float *biasWf, *biasFK, *tokens;
};

__device__ inline void cvt_dev(int idx, const float* x, int Ms, int Ks, int Kp,
                               h16* y, long plane, const float* cs)
{
    const int row = idx / Kp;
    const int col = idx - row * Kp;
    float v = (row < Ms && col < Ks) ? x[(long)row * Ks + col] : 0.f;
    if (cs) v *= cs[col];
    const h16 hi = f2h(v);
    y[idx] = hi;
    y[idx + plane] = f2h(v - (float)hi);
}

__device__ inline void cvtT_dev(int idx, const float* x, int R, int C,
                                h16* y, long plane)
{
    const int row = idx / R;        // src col
    const int col = idx - row * R;  // src row
    const float v = (row < C) ? x[(long)col * C + row] : 0.f;
    const h16 hi = f2h(v);
    y[idx] = hi;
    y[idx + plane] = f2h(v - (float)hi);
}

__global__ __launch_bounds__(256) void setup_all(SetupP p)
{
    long b = blockIdx.x;
    const int t = threadIdx.x;
    if (b < 1024) { cvt_dev((int)(b * 256 + t), p.attn_wq, 512, 512, 512, p.wqb, 512L * 512, p.attn_norm_w); return; }
    b -= 1024;
    if (b < 2048) { cvt_dev((int)(b * 256 + t), p.attn_wkv, 1024, 512, 512, p.wkvb, 1024L * 512, nullptr); return; }
    b -= 2048;
    if (b < 5504) {
        // fkb pair-interleaved + ff_norm fold: row 2i = sim_i, 2i+1 = gate_i
        const int idx = (int)(b * 256 + t);     // < 2752*512
        const int rr = idx >> 9, col = idx & 511;
        const int i = rr >> 1;
        const int src = (rr & 1) ? i + DFF : i;
        float v = 0.f;
        if (i < DFF) v = p.ff_keys_w[(long)src * 512 + col] * p.ff_norm_w[col];
        const h16 hi = f2h(v);
        p.fkb[idx] = hi;
        p.fkb[idx + (long)NFF * 512] = f2h(v - (float)hi);
        return;
    }
    b -= 5504;
    if (b < 1024) { cvt_dev((int)(b * 256 + t), p.res_wq, 512, 512, 512, p.rqb, 512L * 512, p.res_norm_w); return; }
    b -= 1024;
    if (b < 2048) { cvt_dev((int)(b * 256 + t), p.res_wkv, 1024, 512, 512, p.rkvb, 1024L * 512, nullptr); return; }
    b -= 2048;
    if (b < 1024) { cvt_dev((int)(b * 256 + t), p.res_wo, 512, 512, 512, p.rob, 512L * 512, nullptr); return; }
    b -= 1024;
    if (b < 1024) { cvtT_dev((int)(b * 256 + t), p.attn_wo, 512, 512, p.woTb, 512L * 512); return; }
    b -= 1024;
    if (b < 2816) { cvtT_dev((int)(b * 256 + t), p.ff_values_w, 512, DFF, p.fvwTb, (long)KFF * 512); return; }
    b -= 2816;
    if (b < 4) {
        const int n = (int)(b * 256 + t);
        if (n < 1024) {
            float s = 0.f;
            const float* row = p.res_wkv + (long)n * 512;
            for (int dd = 0; dd < 512; ++dd) s = fmaf(row[dd], p.ff_values_b[dd], s);
            p.biasWf[n] = s;
        }
        return;
    }
    b -= 4;
    if (b < 11) {
        const int rr = (int)(b * 256 + t);
        if (rr < 2752) {
            const int i = rr >> 1;
            const int src = (rr & 1) ? i + DFF : i;
            p.biasFK[rr] = (i < DFF) ? p.ff_keys_b[src] : 0.f;
        }
        return;
    }
    b -= 11;
    {   // replicate tokens -> dedup tokens fp32 + tokbf hi/lo (2048 blocks)
        const int idx = (int)(b * 256 + t);
        const float v = p.tok_in[idx & (Bv * Nn_ * Dm - 1)];
        p.tokens[idx] = v;
        const h16 hi = f2h(v);
        p.tokbf[idx] = hi;
        p.tokbf[idx + (long)NTD * Dm] = f2h(v - (float)hi);
    }
}
#define SETUP_BLOCKS 18575

// =====================================================================
// Per-row RMSNorm scale only: rs[r] = rsqrt(mean(x_r^2)+eps). Grid 256.
// =====================================================================
__global__ __launch_bounds__(256) void rs_kernel(const float* __restrict__ x,
                                                 float* __restrict__ rs)
{
    const int r = blockIdx.x * 4 + (threadIdx.x >> 6);
    const int lane = threadIdx.x & 63;
    const float* row = x + (long)r * Dm + lane * 8;
    float ss = 0.f;
    #pragma unroll
    for (int i = 0; i < 8; i += 4) {
        const float4 v = *(const float4*)(row + i);
        ss += v.x * v.x + v.y * v.y + v.z * v.z + v.w * v.w;
    }
    #pragma unroll
    for (int off = 32; off > 0; off >>= 1) ss += __shfl_xor(ss, off, 64);
    if (lane == 0) rs[r] = rsqrtf(ss * (1.f / 512.f) + EPSR);
}

// =====================================================================
// MFMA flash self-attention (attention only). Grid = 128; 256 thr.
// =====================================================================
__global__ __launch_bounds__(256) void attn_self_mfma(
    const h16* __restrict__ qhl, const h16* __restrict__ khl,
    const h16* __restrict__ vtb, long pl, h16* __restrict__ outbf)
{
    __shared__ h16 kh[4096], kl[4096], vh[4096], vl[4096];
    __shared__ h16 pH[4 * 1024], pL[4 * 1024];

    const int bat = blockIdx.x >> 5;
    const int head = (blockIdx.x >> 2) & 7;
    const int qc = blockIdx.x & 3;
    const int t = threadIdx.x;
    const int w = t >> 6, lane = t & 63;
    const int row16 = lane & 15, quad = lane >> 4;

    v8h qh[2], ql[2];
    {
        const long qrow = (long)bat * 256 + qc * 64 + w * 16 + row16;
        const h16* qp = qhl + qrow * 512 + head * 64 + quad * 8;
        qh[0] = *(const v8h*)qp;        qh[1] = *(const v8h*)(qp + 32);
        ql[0] = *(const v8h*)(qp + pl); ql[1] = *(const v8h*)(qp + pl + 32);
    }

    v4f O[4];
    #pragma unroll
    for (int i = 0; i < 4; ++i) O[i] = (v4f){0.f, 0.f, 0.f, 0.f};
    float m[4] = {-1e30f, -1e30f, -1e30f, -1e30f};
    float l[4] = {0.f, 0.f, 0.f, 0.f};

    const int sj = t >> 3;
    const int sc = t & 7;
    const long kbase = ((long)bat * 256) * 512 + head * 64;
    const long vbase = ((long)(bat * 8 + head) * 64) << 8;

    for (int jc = 0; jc < 256; jc += 64) {
        __syncthreads();
        #pragma unroll
        for (int rep = 0; rep < 2; ++rep) {
            const int row = sj + rep * 32;
            const int dsw = row * 64 + ((sc ^ (row & 7)) * 8);
            const h16* ks = khl + kbase + (long)(jc + row) * 512 + sc * 8;
            const h16* vs = vtb + vbase + ((long)row << 8) + jc + sc * 8;
            *(v8h*)&kh[dsw] = *(const v8h*)ks;
            *(v8h*)&kl[dsw] = *(const v8h*)(ks + pl);
            *(v8h*)&vh[dsw] = *(const v8h*)vs;
            *(v8h*)&vl[dsw] = *(const v8h*)(vs + pl);
        }
        __syncthreads();

        v4f S[4];
        #pragma unroll
        for (int i = 0; i < 4; ++i) S[i] = (v4f){0.f, 0.f, 0.f, 0.f};
        #pragma unroll
        for (int kk = 0; kk < 2; ++kk) {
            #pragma unroll
            for (int tile = 0; tile < 4; ++tile) {
                const int off = (tile * 16 + row16) * 64 + (((kk * 4 + quad) ^ (row16 & 7)) * 8);
                v8h bh = *(const v8h*)&kh[off];
                v8h bl = *(const v8h*)&kl[off];
                S[tile] = __builtin_amdgcn_mfma_f32_16x16x32_f16(qh[kk], bh, S[tile], 0, 0, 0);
                S[tile] = __builtin_amdgcn_mfma_f32_16x16x32_f16(qh[kk], bl, S[tile], 0, 0, 0);
                S[tile] = __builtin_amdgcn_mfma_f32_16x16x32_f16(ql[kk], bh, S[tile], 0, 0, 0);
            }
        }

        float mc[4], sums[4], alpha[4];
        #pragma unroll
        for (int r = 0; r < 4; ++r) {
            float v = fmaxf(fmaxf(S[0][r], S[1][r]), fmaxf(S[2][r], S[3][r]));
            v = fmaxf(v, __shfl_xor(v, 1, 64));
            v = fmaxf(v, __shfl_xor(v, 2, 64));
            v = fmaxf(v, __shfl_xor(v, 4, 64));
            v = fmaxf(v, __shfl_xor(v, 8, 64));
            mc[r] = v;
        }
        #pragma unroll
        for (int r = 0; r < 4; ++r) {
            const float mn = fmaxf(m[r], mc[r]);
            alpha[r] = __expf(m[r] - mn);
            m[r] = mn;
            sums[r] = 0.f;
        }
        #pragma unroll
        for (int tile = 0; tile < 4; ++tile) {
            #pragma unroll
            for (int r = 0; r < 4; ++r) {
                const float p = __expf(S[tile][r] - m[r]);
                S[tile][r] = p;
                sums[r] += p;
            }
        }
        #pragma unroll
        for (int r = 0; r < 4; ++r) {
            float v = sums[r];
            v += __shfl_xor(v, 1, 64);
            v += __shfl_xor(v, 2, 64);
            v += __shfl_xor(v, 4, 64);
            v += __shfl_xor(v, 8, 64);
            l[r] = l[r] * alpha[r] + v;
        }
        #pragma unroll
        for (int tile = 0; tile < 4; ++tile)
            #pragma unroll
            for (int r = 0; r < 4; ++r) O[tile][r] *= alpha[r];

        #pragma unroll
        for (int tile = 0; tile < 4; ++tile) {
            const int chunkcol = tile * 2 + (row16 >> 3);
            #pragma unroll
            for (int r = 0; r < 4; ++r) {
                const int prow = quad * 4 + r;
                const int addr = w * 1024 + prow * 64 +
                                 ((chunkcol ^ (prow & 7)) * 8) + (row16 & 7);
                const float p = S[tile][r];
                const h16 hi = f2h(p);
                pH[addr] = hi;
                pL[addr] = f2h(p - (float)hi);
            }
        }

        #pragma unroll
        for (int kk = 0; kk < 2; ++kk) {
            const int poff = w * 1024 + row16 * 64 + (((kk * 4 + quad) ^ (row16 & 7)) * 8);
            v8h pa = *(const v8h*)&pH[poff];
            v8h pb = *(const v8h*)&pL[poff];
            #pragma unroll
            for (int tile = 0; tile < 4; ++tile) {
                const int off = (tile * 16 + row16) * 64 + (((kk * 4 + quad) ^ (row16 & 7)) * 8);
                v8h vbh = *(const v8h*)&vh[off];
                v8h vbl = *(const v8h*)&vl[off];
                O[tile] = __builtin_amdgcn_mfma_f32_16x16x32_f16(pa, vbh, O[tile], 0, 0, 0);
                O[tile] = __builtin_amdgcn_mfma_f32_16x16x32_f16(pa, vbl, O[tile], 0, 0, 0);
                O[tile] = __builtin_amdgcn_mfma_f32_16x16x32_f16(pb, vbh, O[tile], 0, 0, 0);
            }
        }
    }

    #pragma unroll
    for (int tile = 0; tile < 4; ++tile) {
        const int dim = tile * 16 + row16;
        #pragma unroll
        for (int r = 0; r < 4; ++r) {
            const long grow = (long)bat * 256 + qc * 64 + w * 16 + quad * 4 + r;
            const float v = O[tile][r] / l[r];
            const long idx = grow * 512 + head * 64 + dim;
            const h16 hi = f2h(v);
            outbf[idx] = hi;
            outbf[idx + pl] = f2h(v - (float)hi);
        }
    }
}

// =====================================================================
// Pooled attention over distinct ctx entries. Block per (rb, head);
// 128 thr = 2 waves (one per bb). kvc3 rows: [rb*NMD + md][1024].
// =====================================================================
template <int M>
__global__ __launch_bounds__(128) void attn_pool_kernel(
    const float* __restrict__ qb, const float* __restrict__ kvc3,
    h16* __restrict__ outbf, long plane)
{
    const int rb = blockIdx.x >> 3;
    const int h = blockIdx.x & 7;
    __shared__ float k_lds[M * 66];
    __shared__ float v_lds[M * 66];
    __shared__ float q_lds[2 * 64];
    __shared__ float p_lds[2 * 64];
    const int t = threadIdx.x;
    const int g = rb >> 8, nn = rb & 255;

    for (int idx = t; idx < M * 64; idx += 128) {
        const int m = idx >> 6, d = idx & 63;
        const long base = ((long)rb * NMD + m) * 1024 + h * DH + d;
        k_lds[m * 66 + d] = kvc3[base];
        v_lds[m * 66 + d] = kvc3[base + 512];
    }
    {
        const int w = t >> 6, dd = t & 63;
        const long iq = (long)(g * 2 + w) * 256 + nn;
        q_lds[t] = qb[iq * Dm + h * DH + dd];
    }
    __syncthreads();

    const int w = t >> 6;
    const int lane = t & 63;
    float s = -1e30f;
    if (lane < M) {
        s = 0.f;
        const float* kr = &k_lds[lane * 66];
        const float* qr = &q_lds[w * 64];
        #pragma unroll
        for (int dd = 0; dd < 64; dd += 2) {
            s = fmaf(qr[dd], kr[dd], s);
            s = fmaf(qr[dd + 1], kr[dd + 1], s);
        }
    }
    float mx = s;
    #pragma unroll
    for (int off = 32; off > 0; off >>= 1) mx = fmaxf(mx, __shfl_xor(mx, off, 64));
    const float p = __expf(s - mx);
    float l = p;
    #pragma unroll
    for (int off = 32; off > 0; off >>= 1) l += __shfl_xor(l, off, 64);
    p_lds[w * 64 + lane] = p / l;

    float o = 0.f;
    const float* pr = &p_lds[w * 64];
    #pragma unroll
    for (int m = 0; m < M; ++m)
        o = fmaf(pr[m], v_lds[m * 66 + lane], o);

    const long iq = (long)(g * 2 + w) * 256 + nn;
    const long oidx = iq * Dm + h * DH + lane;
    const h16 hi = f2h(o);
    outbf[oidx] = hi;
    outbf[oidx + plane] = f2h(o - (float)hi);
}

// =====================================================================
extern "C" void kernel_launch(void* const* d_in, const int* in_sizes, int n_in,
                              void* d_out, int out_size, void* d_ws, size_t ws_size,
                              hipStream_t stream)
{
    const float* tok_in       = (const float*)d_in[0];
    const float* attn_norm_w  = (const float*)d_in[1];
    const float* attn_wq      = (const float*)d_in[2];
    const float* attn_wkv     = (const float*)d_in[3];
    const float* attn_wo      = (const float*)d_in[4];
    const float* ff_norm_w    = (const float*)d_in[5];
    const float* ff_keys_w    = (const float*)d_in[6];
    const float* ff_keys_b    = (const float*)d_in[7];
    const float* ff_values_w  = (const float*)d_in[8];
    const float* ff_values_b  = (const float*)d_in[9];
    const float* res_norm_w   = (const float*)d_in[10];
    const float* res_wq       = (const float*)d_in[11];
    const float* res_wkv      = (const float*)d_in[12];
    const float* res_wo       = (const float*)d_in[13];

    float* ws = (float*)d_ws;
    float* kvc3   = ws;                                  // 512*14*1024
    float* tokens = kvc3 + 512L * NMD * 1024;            // NTD*512
    float* qbuf   = tokens + (long)NTD * Dm;             // NTD*512
    float* biasWf = qbuf + (long)NTD * Dm;               // 1024
    float* biasFK = biasWf + 1024;                       // 2752
    float* rsbuf  = biasFK + 2752;                       // 1024

    h16* us = (h16*)(rsbuf + 1024);
    const long apl = (long)NTD * Dm;
    const long hpl = (long)NTD * KFF;
    const long w1 = 512L * 512, w2 = 1024L * 512, w3 = (long)NFF * 512;
    const long w5 = (long)KFF * 512;
    const long wa_pl = 1024L * 512;
    const long wf_pl = 1024L * KFF;
    h16* tokbf = us; us += 2 * apl;
    h16* abf   = us; us += 2 * apl;
    h16* hbf   = us; us += 2 * hpl;
    h16* qhl   = us; us += 2 * apl;
    h16* khl   = us; us += 2 * apl;
    h16* vtb   = us; us += 2 * apl;
    h16* wqb   = us; us += 2 * w1;
    h16* wkvb  = us; us += 2 * w2;
    h16* fkb   = us; us += 2 * w3;
    h16* rqb   = us; us += 2 * w1;
    h16* rkvb  = us; us += 2 * w2;
    h16* rob   = us; us += 2 * w1;
    h16* woTb  = us; us += 2 * w1;
    h16* fvwTb = us; us += 2 * w5;
    h16* Wab   = us; us += 2 * wa_pl;
    h16* Wfb   = us; us += 2 * wf_pl;

    // ---- fused setup (weights + folds + replicate), one dispatch ----
    {
        SetupP p;
        p.attn_wq = attn_wq; p.attn_wkv = attn_wkv; p.ff_keys_w = ff_keys_w;
        p.ff_keys_b = ff_keys_b; p.res_wq = res_wq; p.res_wkv = res_wkv;
        p.res_wo = res_wo; p.attn_wo = attn_wo; p.ff_values_w = ff_values_w;
        p.ff_values_b = ff_values_b;
        p.attn_norm_w = attn_norm_w; p.ff_norm_w = ff_norm_w; p.res_norm_w = res_norm_w;
        p.tok_in = tok_in;
        p.wqb = wqb; p.wkvb = wkvb; p.fkb = fkb; p.rqb = rqb; p.rkvb = rkvb;
        p.rob = rob; p.woTb = woTb; p.fvwTb = fvwTb; p.tokbf = tokbf;
        p.biasWf = biasWf; p.biasFK = biasFK; p.tokens = tokens;
        setup_all<<<SETUP_BLOCKS, 256, 0, stream>>>(p);
    }

    auto mk = [](const h16* A, long Apl, int lda,
                 const h16* W, long Wpl, int ldw,
                 const float* bias, const float* rss,
                 float* C, int ldc, int Nd,
                 h16* Cbf, long bfpl, int mbase, int K,
                 int mode, int nbx) -> GDesc {
        GDesc d;
        d.A = A; d.Apl = Apl; d.lda = lda;
        d.W = W; d.Wpl = Wpl; d.ldw = ldw;
        d.bias = bias; d.rss = rss; d.C = C; d.ldc = ldc; d.Nd = Nd;
        d.Cbf = Cbf; d.bfpl = bfpl; d.mbase = mbase; d.K = K;
        d.mode = mode; d.nbx = nbx;
        return d;
    };

    // ---- fold batch: Wf(352) + Wa(128) + constant e0 token-KV(256) ----
    {
        GDesc dWf = mk(rkvb, w2, 512, fvwTb, w5, 512, nullptr, nullptr, nullptr, KFF, KFF,
                       Wfb, wf_pl, 0, 512, 1, 16);
        GDesc dWa = mk(rkvb, w2, 512, woTb, w1, 512, nullptr, nullptr, nullptr, 512, 512,
                       Wab, wa_pl, 0, 512, 1, 16);
        GDesc dtokKV = mk(tokbf, apl, 512, rkvb, w2, 512, nullptr, nullptr, kvc3, 1024, 1024,
                          nullptr, 0, 0, 512, 3, 16);
        mega_gemm<64, 64><<<736, 256, 0, stream>>>(dWf, dWa, dtokKV, dtokKV, 352, 480, 736);
    }

    for (int e = 0; e < 3; ++e) {
        rs_kernel<<<256, 256, 0, stream>>>(tokens, rsbuf);
        // ---- B1: ffk+GLU(688) + wkv K/V^T(256) + wq(128) + rq(128) = 1200 ----
        {
            GDesc dffk = mk(tokbf, apl, 512, fkb,  w3, 512, biasFK, rsbuf, nullptr, KFF, DFF2,
                            hbf, hpl, 0, 512, 6, 16);
            GDesc dwkv = mk(tokbf, apl, 512, wkvb, w2, 512, nullptr, nullptr, (float*)vtb, 1024, 1024,
                            khl, apl, 0, 512, 4, 16);
            GDesc dwq  = mk(tokbf, apl, 512, wqb,  w1, 512, nullptr, rsbuf, nullptr, 512, 512,
                            qhl, apl, 0, 512, 1, 16);
            GDesc drq  = mk(tokbf, apl, 512, rqb,  w1, 512, nullptr, rsbuf, qbuf, 512, 512,
                            nullptr, 0, 0, 512, 0, 16);
            mega_gemm<64, 64><<<1200, 256, 0, stream>>>(dffk, dwkv, dwq, drq, 688, 944, 1072);
        }
        // ---- self-attention ----
        attn_self_mfma<<<128, 256, 0, stream>>>(qhl, khl, vtb, apl, abf);
        // ---- B2: ffv-kv(256) + wo-kv(256) ----
        {
            GDesc dffvKV = mk(hbf, hpl, KFF, Wfb, wf_pl, KFF, biasWf, nullptr, kvc3, 1024, 1024,
                              nullptr, 0, 2 + 2 * e, KFF, 3, 16);
            GDesc dwoKV  = mk(abf, apl, 512, Wab, wa_pl, 512, nullptr, nullptr, kvc3, 1024, 1024,
                              nullptr, 0, 1 + 2 * e, 512, 3, 16);
            mega_gemm<64, 64><<<512, 256, 0, stream>>>(dffvKV, dwoKV, dwoKV, dwoKV, 256, 512, 512);
        }
        // ---- pooled attention ----
        if (e == 0)      attn_pool_kernel<6><<<512 * NH, 128, 0, stream>>>(qbuf, kvc3, abf, apl);
        else if (e == 1) attn_pool_kernel<10><<<512 * NH, 128, 0, stream>>>(qbuf, kvc3, abf, apl);
        else             attn_pool_kernel<14><<<512 * NH, 128, 0, stream>>>(qbuf, kvc3, abf, apl);
        // ---- B4: ro (BM=32, BN=128, 128 blocks) ----
        {
            if (e < 2) {
                GDesc dro = mk(abf, apl, 512, rob, w1, 512, nullptr, nullptr, tokens, 512, 512,
                               tokbf, apl, 0, 512, 2, 32);
                mega_gemm<32, 128><<<128, 256, 0, stream>>>(dro, dro, dro, dro, 128, 128, 128);
            } else {
                GDesc dro = mk(abf, apl, 512, rob, w1, 512, nullptr, nullptr, (float*)d_out, 512, 512,
                               nullptr, 0, 0, 512, 5, 32);
                mega_gemm<32, 128><<<128, 256, 0, stream>>>(dro, dro, dro, dro, 128, 128, 128);
            }
        }
    }
}

// Round 14
// 465.529 us; speedup vs baseline: 1.0200x; 1.0200x over previous
//
#include <hip/hip_runtime.h>
#include <math.h>

// ---- problem constants ----
#define Dm   512
#define Nn_  256
#define Bv   2
#define NTD  1024          // dedup rows: (group g, batch bb, pos nn)
#define NH   8
#define DH   64
#define DFF  1365
#define DFF2 2730
#define KFF  1408
#define NFF  2816
#define NMD  14            // max distinct pooled-context entries
#define EPSR 1.1920929e-07f

typedef _Float16 h16;
typedef h16  v8h  __attribute__((ext_vector_type(8)));
typedef float v4f __attribute__((ext_vector_type(4)));

__device__ inline h16 f2h(float v) { return (h16)v; }

__device__ inline void glds16(const void* g, void* l) {
    __builtin_amdgcn_global_load_lds((const __attribute__((address_space(1))) void*)g,
                                     (__attribute__((address_space(3))) void*)l, 16, 0, 0);
}

// =====================================================================
// GEMM body (device), fp16 3-term compensated, double-buffered LDS.
// rss: per-row sum-of-squares -> v *= rsqrt(rss/512+eps) (folded RMSNorm).
// ssqn: accumulate per-row sum(v^2) via atomics (feeds next exchange's rss).
// modes: 0 fp32 C; 1 fp16 hi/lo Cbf; 3 pooled-ctx remap; 4 attn KV split;
// 5 final 3-copy expand; 6 fused GLU-GELU (paired cols).
// =====================================================================
struct GDesc {
    const h16* A;
    const h16* W;
    const float* bias;
    const float* rss;
    float* ssqn;
    float* C;
    h16* Cbf;
    long Apl, Wpl, bfpl;
    int lda, ldw, ldc, Nd, mbase, K, mode, nbx;
};

template <int BM, int BN>
__device__ void gemm_body(const GDesc& d, int lb, h16* lds)
{
    constexpr int NWN = (BN == 128) ? 2 : 1;
    constexpr int NWM = 4 / NWN;
    constexpr int MI = BM / (16 * NWM);
    constexpr int ABUF = BM * 32;
    constexpr int WBUFh = BN * 32;
    constexpr int BUF = 2 * ABUF + 2 * WBUFh;
    constexpr int ASEG = BM / 16;
    constexpr int WSEG = BN / 16;
    constexpr int NSEG = 2 * ASEG + 2 * WSEG;

    const int bx = lb % d.nbx;
    const int by = lb / d.nbx;

    const int tid = threadIdx.x;
    const int wid = tid >> 6;
    const int lane = tid & 63;
    const int wm = wid / NWN, wn = wid % NWN;
    const int row16 = lane & 15, quad = lane >> 4;
    const long i0 = (long)bx * BM;
    const long j0 = (long)by * BN;
    const int l4 = lane >> 2;
    const int l2s = ((lane & 3) ^ (l4 & 3)) * 8;
    const int ksw = (quad ^ (row16 & 3)) * 8;

    auto stage = [&](int k0, h16* buf) {
        #pragma unroll
        for (int s = 0; s < NSEG / 4; ++s) {
            const int sg = wid * (NSEG / 4) + s;
            const h16* src;
            int dst;
            if (sg < ASEG) {
                src = d.A + (i0 + sg * 16 + l4) * (long)d.lda + k0 + l2s;
                dst = sg * 512;
            } else if (sg < 2 * ASEG) {
                const int r = sg - ASEG;
                src = d.A + d.Apl + (i0 + r * 16 + l4) * (long)d.lda + k0 + l2s;
                dst = ABUF + r * 512;
            } else if (sg < 2 * ASEG + WSEG) {
                const int r = sg - 2 * ASEG;
                src = d.W + (j0 + r * 16 + l4) * (long)d.ldw + k0 + l2s;
                dst = 2 * ABUF + r * 512;
            } else {
                const int r = sg - 2 * ASEG - WSEG;
                src = d.W + d.Wpl + (j0 + r * 16 + l4) * (long)d.ldw + k0 + l2s;
                dst = 2 * ABUF + WBUFh + r * 512;
            }
            glds16(src, &buf[dst]);
        }
    };

    v4f acc[MI][4];
    #pragma unroll
    for (int a = 0; a < MI; ++a)
        #pragma unroll
        for (int b = 0; b < 4; ++b) acc[a][b] = (v4f){0.f, 0.f, 0.f, 0.f};

    stage(0, lds);
    int cur = 0;
    for (int k0 = 0; k0 < d.K; k0 += 32) {
        __syncthreads();
        h16* cbuf = &lds[cur * BUF];
        if (k0 + 32 < d.K) stage(k0 + 32, &lds[(cur ^ 1) * BUF]);

        v8h af[MI], al[MI];
        #pragma unroll
        for (int mi = 0; mi < MI; ++mi) {
            const int aoff = (wm * (16 * MI) + mi * 16 + row16) * 32 + ksw;
            af[mi] = *(const v8h*)&cbuf[aoff];
            al[mi] = *(const v8h*)&cbuf[ABUF + aoff];
        }
        #pragma unroll
        for (int nj = 0; nj < 4; ++nj) {
            const int boff = (wn * 64 + nj * 16 + row16) * 32 + ksw;
            v8h bh = *(const v8h*)&cbuf[2 * ABUF + boff];
            v8h bl = *(const v8h*)&cbuf[2 * ABUF + WBUFh + boff];
            #pragma unroll
            for (int mi = 0; mi < MI; ++mi) {
                acc[mi][nj] = __builtin_amdgcn_mfma_f32_16x16x32_f16(af[mi], bh, acc[mi][nj], 0, 0, 0);
                acc[mi][nj] = __builtin_amdgcn_mfma_f32_16x16x32_f16(af[mi], bl, acc[mi][nj], 0, 0, 0);
                acc[mi][nj] = __builtin_amdgcn_mfma_f32_16x16x32_f16(al[mi], bh, acc[mi][nj], 0, 0, 0);
            }
        }
        cur ^= 1;
    }

    float sqacc[MI][4];
    #pragma unroll
    for (int a = 0; a < MI; ++a)
        #pragma unroll
        for (int r = 0; r < 4; ++r) sqacc[a][r] = 0.f;

    #pragma unroll
    for (int nj = 0; nj < 4; ++nj) {
        const int col = (int)j0 + wn * 64 + nj * 16 + row16;
        if (col < d.Nd) {
            const float bv = d.bias ? d.bias[col] : 0.f;
            #pragma unroll
            for (int mi = 0; mi < MI; ++mi) {
                #pragma unroll
                for (int r = 0; r < 4; ++r) {
                    const long row = i0 + wm * (16 * MI) + mi * 16 + quad * 4 + r;
                    float v = acc[mi][nj][r];
                    if (d.rss) v *= rsqrtf(d.rss[(int)row] * (1.f / 512.f) + EPSR);
                    v += bv;
                    if (d.ssqn) sqacc[mi][r] += v * v;
                    if (d.mode == 0) {
                        d.C[row * (long)d.ldc + col] = v;
                    } else if (d.mode == 1) {
                        const long idx = row * (long)d.ldc + col;
                        const h16 hi = f2h(v);
                        d.Cbf[idx] = hi; d.Cbf[idx + d.bfpl] = f2h(v - (float)hi);
                    } else if (d.mode == 3) {
                        const int rr = (int)row & 1023;
                        const int md = d.mbase * 2 + (rr >> 9);
                        const long orow = (long)(((rr >> 8) & 1) * 256 + (rr & 255)) * NMD + md;
                        d.C[orow * 1024 + col] = v;
                    } else if (d.mode == 4) {
                        const h16 hi = f2h(v);
                        const h16 lo = f2h(v - (float)hi);
                        if (col < 512) {
                            const long idx = row * 512 + col;
                            d.Cbf[idx] = hi; d.Cbf[idx + d.bfpl] = lo;
                        } else {
                            const int c = col - 512;
                            const int bh_ = ((int)(row >> 8)) * 8 + (c >> 6);
                            const long idx = (((long)bh_ * 64 + (c & 63)) << 8) + (row & 255);
                            h16* vtp = (h16*)d.C;
                            vtp[idx] = hi; vtp[idx + d.bfpl] = lo;
                        }
                    } else if (d.mode == 5) {
                        const int g = (int)(row >> 9), bb = ((int)row >> 8) & 1, nn = (int)row & 255;
                        #pragma unroll
                        for (int rep = 0; rep < 3; ++rep) {
                            const long orow = (long)(((g * 3 + rep) * 2 + bb) * 256 + nn);
                            d.C[orow * (long)d.ldc + col] = v;
                        }
                    } else {
                        // mode 6: paired (sim,gate) cols; even lane writes
                        // sim*gelu(gate) to Cbf[row][col>>1] hi/lo.
                        const float gt = __shfl_xor(v, 1, 64);
                        if ((col & 1) == 0) {
                            const float ge = 0.5f * gt * (1.f + erff(gt * 0.70710678118654752440f));
                            const float out = v * ge;
                            const long idx = row * (long)d.ldc + (col >> 1);
                            const h16 hi = f2h(out);
                            d.Cbf[idx] = hi; d.Cbf[idx + d.bfpl] = f2h(out - (float)hi);
                        }
                    }
                }
            }
        }
    }

    if (d.ssqn) {
        #pragma unroll
        for (int mi = 0; mi < MI; ++mi)
            #pragma unroll
            for (int r = 0; r < 4; ++r) {
                float s = sqacc[mi][r];
                s += __shfl_xor(s, 1, 64);
                s += __shfl_xor(s, 2, 64);
                s += __shfl_xor(s, 4, 64);
                s += __shfl_xor(s, 8, 64);
                if (row16 == 0) {
                    const long row = i0 + wm * (16 * MI) + mi * 16 + quad * 4 + r;
                    atomicAdd(&d.ssqn[row], s);
                }
            }
    }
}

template <int BM, int BN>
__global__ __launch_bounds__(256) void mega_gemm(GDesc d0, GDesc d1, GDesc d2, GDesc d3,
                                                 int n0, int n01, int n012)
{
    constexpr int BUF2 = 2 * (2 * BM * 32 + 2 * BN * 32);
    __shared__ h16 lds[BUF2];
    GDesc d; int lb = blockIdx.x;
    if (lb < n0) d = d0;
    else if (lb < n01) { d = d1; lb -= n0; }
    else if (lb < n012) { d = d2; lb -= n01; }
    else { d = d3; lb -= n012; }
    gemm_body<BM, BN>(d, lb, lds);
}

// =====================================================================
// MFMA flash self-attention body (device). smem: 24576 h16 (48 KB).
// =====================================================================
__device__ void attn_body(const h16* __restrict__ qhl, const h16* __restrict__ khl,
                          const h16* __restrict__ vtb, long pl,
                          h16* __restrict__ outbf, h16* smem)
{
    h16* kh = smem;
    h16* kl = smem + 4096;
    h16* vh = smem + 8192;
    h16* vl = smem + 12288;
    h16* pH = smem + 16384;
    h16* pL = smem + 20480;

    const int bat = blockIdx.x >> 5;
    const int head = (blockIdx.x >> 2) & 7;
    const int qc = blockIdx.x & 3;
    const int t = threadIdx.x;
    const int w = t >> 6, lane = t & 63;
    const int row16 = lane & 15, quad = lane >> 4;

    v8h qh[2], ql[2];
    {
        const long qrow = (long)bat * 256 + qc * 64 + w * 16 + row16;
        const h16* qp = qhl + qrow * 512 + head * 64 + quad * 8;
        qh[0] = *(const v8h*)qp;        qh[1] = *(const v8h*)(qp + 32);
        ql[0] = *(const v8h*)(qp + pl); ql[1] = *(const v8h*)(qp + pl + 32);
    }

    v4f O[4];
    #pragma unroll
    for (int i = 0; i < 4; ++i) O[i] = (v4f){0.f, 0.f, 0.f, 0.f};
    float m[4] = {-1e30f, -1e30f, -1e30f, -1e30f};
    float l[4] = {0.f, 0.f, 0.f, 0.f};

    const int sj = t >> 3;
    const int sc = t & 7;
    const long kbase = ((long)bat * 256) * 512 + head * 64;
    const long vbase = ((long)(bat * 8 + head) * 64) << 8;

    for (int jc = 0; jc < 256; jc += 64) {
        __syncthreads();
        #pragma unroll
        for (int rep = 0; rep < 2; ++rep) {
            const int row = sj + rep * 32;
            const int dsw = row * 64 + ((sc ^ (row & 7)) * 8);
            const h16* ks = khl + kbase + (long)(jc + row) * 512 + sc * 8;
            const h16* vs = vtb + vbase + ((long)row << 8) + jc + sc * 8;
            *(v8h*)&kh[dsw] = *(const v8h*)ks;
            *(v8h*)&kl[dsw] = *(const v8h*)(ks + pl);
            *(v8h*)&vh[dsw] = *(const v8h*)vs;
            *(v8h*)&vl[dsw] = *(const v8h*)(vs + pl);
        }
        __syncthreads();

        v4f S[4];
        #pragma unroll
        for (int i = 0; i < 4; ++i) S[i] = (v4f){0.f, 0.f, 0.f, 0.f};
        #pragma unroll
        for (int kk = 0; kk < 2; ++kk) {
            #pragma unroll
            for (int tile = 0; tile < 4; ++tile) {
                const int off = (tile * 16 + row16) * 64 + (((kk * 4 + quad) ^ (row16 & 7)) * 8);
                v8h bh = *(const v8h*)&kh[off];
                v8h bl = *(const v8h*)&kl[off];
                S[tile] = __builtin_amdgcn_mfma_f32_16x16x32_f16(qh[kk], bh, S[tile], 0, 0, 0);
                S[tile] = __builtin_amdgcn_mfma_f32_16x16x32_f16(qh[kk], bl, S[tile], 0, 0, 0);
                S[tile] = __builtin_amdgcn_mfma_f32_16x16x32_f16(ql[kk], bh, S[tile], 0, 0, 0);
            }
        }

        float mc[4], sums[4], alpha[4];
        #pragma unroll
        for (int r = 0; r < 4; ++r) {
            float v = fmaxf(fmaxf(S[0][r], S[1][r]), fmaxf(S[2][r], S[3][r]));
            v = fmaxf(v, __shfl_xor(v, 1, 64));
            v = fmaxf(v, __shfl_xor(v, 2, 64));
            v = fmaxf(v, __shfl_xor(v, 4, 64));
            v = fmaxf(v, __shfl_xor(v, 8, 64));
            mc[r] = v;
        }
        #pragma unroll
        for (int r = 0; r < 4; ++r) {
            const float mn = fmaxf(m[r], mc[r]);
            alpha[r] = __expf(m[r] - mn);
            m[r] = mn;
            sums[r] = 0.f;
        }
        #pragma unroll
        for (int tile = 0; tile < 4; ++tile) {
            #pragma unroll
            for (int r = 0; r < 4; ++r) {
                const float p = __expf(S[tile][r] - m[r]);
                S[tile][r] = p;
                sums[r] += p;
            }
        }
        #pragma unroll
        for (int r = 0; r < 4; ++r) {
            float v = sums[r];
            v += __shfl_xor(v, 1, 64);
            v += __shfl_xor(v, 2, 64);
            v += __shfl_xor(v, 4, 64);
            v += __shfl_xor(v, 8, 64);
            l[r] = l[r] * alpha[r] + v;
        }
        #pragma unroll
        for (int tile = 0; tile < 4; ++tile)
            #pragma unroll
            for (int r = 0; r < 4; ++r) O[tile][r] *= alpha[r];

        #pragma unroll
        for (int tile = 0; tile < 4; ++tile) {
            const int chunkcol = tile * 2 + (row16 >> 3);
            #pragma unroll
            for (int r = 0; r < 4; ++r) {
                const int prow = quad * 4 + r;
                const int addr = w * 1024 + prow * 64 +
                                 ((chunkcol ^ (prow & 7)) * 8) + (row16 & 7);
                const float p = S[tile][r];
                const h16 hi = f2h(p);
                pH[addr] = hi;
                pL[addr] = f2h(p - (float)hi);
            }
        }

        #pragma unroll
        for (int kk = 0; kk < 2; ++kk) {
            const int poff = w * 1024 + row16 * 64 + (((kk * 4 + quad) ^ (row16 & 7)) * 8);
            v8h pa = *(const v8h*)&pH[poff];
            v8h pb = *(const v8h*)&pL[poff];
            #pragma unroll
            for (int tile = 0; tile < 4; ++tile) {
                const int off = (tile * 16 + row16) * 64 + (((kk * 4 + quad) ^ (row16 & 7)) * 8);
                v8h vbh = *(const v8h*)&vh[off];
                v8h vbl = *(const v8h*)&vl[off];
                O[tile] = __builtin_amdgcn_mfma_f32_16x16x32_f16(pa, vbh, O[tile], 0, 0, 0);
                O[tile] = __builtin_amdgcn_mfma_f32_16x16x32_f16(pa, vbl, O[tile], 0, 0, 0);
                O[tile] = __builtin_amdgcn_mfma_f32_16x16x32_f16(pb, vbh, O[tile], 0, 0, 0);
            }
        }
    }

    #pragma unroll
    for (int tile = 0; tile < 4; ++tile) {
        const int dim = tile * 16 + row16;
        #pragma unroll
        for (int r = 0; r < 4; ++r) {
            const long grow = (long)bat * 256 + qc * 64 + w * 16 + quad * 4 + r;
            const float v = O[tile][r] / l[r];
            const long idx = grow * 512 + head * 64 + dim;
            const h16 hi = f2h(v);
            outbf[idx] = hi;
            outbf[idx + pl] = f2h(v - (float)hi);
        }
    }
}

// Fused: blocks 0..127 attention; 128.. ffv-KV GEMM (BM=64, BN=64).
__global__ __launch_bounds__(256) void attn_ffv(
    GDesc d, const h16* qhl, const h16* khl, const h16* vtb, long pl, h16* outbf)
{
    __shared__ h16 smem[24576];
    if (blockIdx.x < 128) attn_body(qhl, khl, vtb, pl, outbf, smem);
    else gemm_body<64, 64>(d, blockIdx.x - 128, smem);
}

// =====================================================================
// Fused setup: weight converts (+norm folds, pair-interleave, transposes),
// bias folds, ssq0 + ssq zeroing, token replicate. One dispatch.
// =====================================================================
struct SetupP {
    const float *attn_wq, *attn_wkv, *ff_keys_w, *ff_keys_b, *res_wq, *res_wkv,
                *res_wo, *attn_wo, *ff_values_w, *ff_values_b,
                *attn_norm_w, *ff_norm_w, *res_norm_w, *tok_in;
    h16 *wqb, *wkvb, *fkb, *rqb, *rkvb, *rob, *woTb, *fvwTb, *tokbf;
    float *biasWf, *biasFK, *ssq;
};

__device__ inline void cvt_dev(int idx, const float* x, int Ms, int Ks, int Kp,
                               h16* y, long plane, const float* cs)
{
    const int row = idx / Kp;
    const int col = idx - row * Kp;
    float v = (row < Ms && col < Ks) ? x[(long)row * Ks + col] : 0.f;
    if (cs) v *= cs[col];
    const h16 hi = f2h(v);
    y[idx] = hi;
    y[idx + plane] = f2h(v - (float)hi);
}

__device__ inline void cvtT_dev(int idx, const float* x, int R, int C,
                                h16* y, long plane)
{
    const int row = idx / R;
    const int col = idx - row * R;
    const float v = (row < C) ? x[(long)col * C + row] : 0.f;
    const h16 hi = f2h(v);
    y[idx] = hi;
    y[idx + plane] = f2h(v - (float)hi);
}

__global__ __launch_bounds__(256) void setup_all(SetupP p)
{
    long b = blockIdx.x;
    const int t = threadIdx.x;
    if (b < 1024) { cvt_dev((int)(b * 256 + t), p.attn_wq, 512, 512, 512, p.wqb, 512L * 512, p.attn_norm_w); return; }
    b -= 1024;
    if (b < 2048) { cvt_dev((int)(b * 256 + t), p.attn_wkv, 1024, 512, 512, p.wkvb, 1024L * 512, nullptr); return; }
    b -= 2048;
    if (b < 5504) {
        const int idx = (int)(b * 256 + t);
        const int rr = idx >> 9, col = idx & 511;
        const int i = rr >> 1;
        const int src = (rr & 1) ? i + DFF : i;
        float v = 0.f;
        if (i < DFF) v = p.ff_keys_w[(long)src * 512 + col] * p.ff_norm_w[col];
        const h16 hi = f2h(v);
        p.fkb[idx] = hi;
        p.fkb[idx + (long)NFF * 512] = f2h(v - (float)hi);
        return;
    }
    b -= 5504;
    if (b < 1024) { cvt_dev((int)(b * 256 + t), p.res_wq, 512, 512, 512, p.rqb, 512L * 512, p.res_norm_w); return; }
    b -= 1024;
    if (b < 2048) { cvt_dev((int)(b * 256 + t), p.res_wkv, 1024, 512, 512, p.rkvb, 1024L * 512, nullptr); return; }
    b -= 2048;
    if (b < 1024) { cvt_dev((int)(b * 256 + t), p.res_wo, 512, 512, 512, p.rob, 512L * 512, nullptr); return; }
    b -= 1024;
    if (b < 1024) { cvtT_dev((int)(b * 256 + t), p.attn_wo, 512, 512, p.woTb, 512L * 512); return; }
    b -= 1024;
    if (b < 2816) { cvtT_dev((int)(b * 256 + t), p.ff_values_w, 512, DFF, p.fvwTb, (long)KFF * 512); return; }
    b -= 2816;
    if (b < 4) {
        const int n = (int)(b * 256 + t);
        float s = 0.f;
        const float* row = p.res_wkv + (long)n * 512;
        for (int dd = 0; dd < 512; ++dd) s = fmaf(row[dd], p.ff_values_b[dd], s);
        p.biasWf[n] = s;
        return;
    }
    b -= 4;
    if (b < 11) {
        const int rr = (int)(b * 256 + t);
        if (rr < 2752) {
            const int i = rr >> 1;
            const int src = (rr & 1) ? i + DFF : i;
            p.biasFK[rr] = (i < DFF) ? p.ff_keys_b[src] : 0.f;
        }
        return;
    }
    b -= 11;
    if (b < 4) {
        // ssq0[r] = sum of squares of src row (r & 511)
        const int n = (int)(b * 256 + t);
        const float* row = p.tok_in + (long)(n & 511) * 512;
        float s = 0.f;
        for (int dd = 0; dd < 512; ++dd) s = fmaf(row[dd], row[dd], s);
        p.ssq[n] = s;
        return;
    }
    b -= 4;
    if (b < 8) {
        p.ssq[1024 + (int)(b * 256 + t)] = 0.f;   // zero ssq1, ssq2
        return;
    }
    b -= 8;
    {   // replicate tokens -> tokbf hi/lo (2048 blocks)
        const int idx = (int)(b * 256 + t);
        const float v = p.tok_in[idx & (Bv * Nn_ * Dm - 1)];
        const h16 hi = f2h(v);
        p.tokbf[idx] = hi;
        p.tokbf[idx + (long)NTD * Dm] = f2h(v - (float)hi);
    }
}
#define SETUP_BLOCKS 18587

// =====================================================================
// Pooled attention over distinct ctx entries. Block per (rb, head);
// 128 thr = 2 waves (one per bb). kvc3 rows: [rb*NMD + md][1024].
// =====================================================================
template <int M>
__global__ __launch_bounds__(128) void attn_pool_kernel(
    const float* __restrict__ qb, const float* __restrict__ kvc3,
    h16* __restrict__ outbf, long plane)
{
    const int rb = blockIdx.x >> 3;
    const int h = blockIdx.x & 7;
    __shared__ float k_lds[M * 66];
    __shared__ float v_lds[M * 66];
    __shared__ float q_lds[2 * 64];
    __shared__ float p_lds[2 * 64];
    const int t = threadIdx.x;
    const int g = rb >> 8, nn = rb & 255;

    for (int idx = t; idx < M * 64; idx += 128) {
        const int m = idx >> 6, d = idx & 63;
        const long base = ((long)rb * NMD + m) * 1024 + h * DH + d;
        k_lds[m * 66 + d] = kvc3[base];
        v_lds[m * 66 + d] = kvc3[base + 512];
    }
    {
        const int w = t >> 6, dd = t & 63;
        const long iq = (long)(g * 2 + w) * 256 + nn;
        q_lds[t] = qb[iq * Dm + h * DH + dd];
    }
    __syncthreads();

    const int w = t >> 6;
    const int lane = t & 63;
    float s = -1e30f;
    if (lane < M) {
        s = 0.f;
        const float* kr = &k_lds[lane * 66];
        const float* qr = &q_lds[w * 64];
        #pragma unroll
        for (int dd = 0; dd < 64; dd += 2) {
            s = fmaf(qr[dd], kr[dd], s);
            s = fmaf(qr[dd + 1], kr[dd + 1], s);
        }
    }
    float mx = s;
    #pragma unroll
    for (int off = 32; off > 0; off >>= 1) mx = fmaxf(mx, __shfl_xor(mx, off, 64));
    const float p = __expf(s - mx);
    float l = p;
    #pragma unroll
    for (int off = 32; off > 0; off >>= 1) l += __shfl_xor(l, off, 64);
    p_lds[w * 64 + lane] = p / l;

    float o = 0.f;
    const float* pr = &p_lds[w * 64];
    #pragma unroll
    for (int m = 0; m < M; ++m)
        o = fmaf(pr[m], v_lds[m * 66 + lane], o);

    const long iq = (long)(g * 2 + w) * 256 + nn;
    const long oidx = iq * Dm + h * DH + lane;
    const h16 hi = f2h(o);
    outbf[oidx] = hi;
    outbf[oidx + plane] = f2h(o - (float)hi);
}

// =====================================================================
extern "C" void kernel_launch(void* const* d_in, const int* in_sizes, int n_in,
                              void* d_out, int out_size, void* d_ws, size_t ws_size,
                              hipStream_t stream)
{
    const float* tok_in       = (const float*)d_in[0];
    const float* attn_norm_w  = (const float*)d_in[1];
    const float* attn_wq      = (const float*)d_in[2];
    const float* attn_wkv     = (const float*)d_in[3];
    const float* attn_wo      = (const float*)d_in[4];
    const float* ff_norm_w    = (const float*)d_in[5];
    const float* ff_keys_w    = (const float*)d_in[6];
    const float* ff_keys_b    = (const float*)d_in[7];
    const float* ff_values_w  = (const float*)d_in[8];
    const float* ff_values_b  = (const float*)d_in[9];
    const float* res_norm_w   = (const float*)d_in[10];
    const float* res_wq       = (const float*)d_in[11];
    const float* res_wkv      = (const float*)d_in[12];
    const float* res_wo       = (const float*)d_in[13];

    float* ws = (float*)d_ws;
    float* kvc3   = ws;                                  // 512*14*1024
    float* qbuf   = kvc3 + 512L * NMD * 1024;            // NTD*512
    float* biasWf = qbuf + (long)NTD * Dm;               // 1024
    float* biasFK = biasWf + 1024;                       // 2752
    float* ssq    = biasFK + 2752;                       // 3*1024

    h16* us = (h16*)(ssq + 3 * 1024);
    const long apl = (long)NTD * Dm;
    const long hpl = (long)NTD * KFF;
    const long w1 = 512L * 512, w2 = 1024L * 512, w3 = (long)NFF * 512;
    const long w5 = (long)KFF * 512;
    const long wa_pl = 1024L * 512;
    const long wf_pl = 1024L * KFF;
    h16* tokbf = us; us += 2 * apl;
    h16* abf   = us; us += 2 * apl;
    h16* hbf   = us; us += 2 * hpl;
    h16* qhl   = us; us += 2 * apl;
    h16* khl   = us; us += 2 * apl;
    h16* vtb   = us; us += 2 * apl;
    h16* wqb   = us; us += 2 * w1;
    h16* wkvb  = us; us += 2 * w2;
    h16* fkb   = us; us += 2 * w3;
    h16* rqb   = us; us += 2 * w1;
    h16* rkvb  = us; us += 2 * w2;
    h16* rob   = us; us += 2 * w1;
    h16* woTb  = us; us += 2 * w1;
    h16* fvwTb = us; us += 2 * w5;
    h16* Wab   = us; us += 2 * wa_pl;
    h16* Wfb   = us; us += 2 * wf_pl;

    // ---- fused setup ----
    {
        SetupP p;
        p.attn_wq = attn_wq; p.attn_wkv = attn_wkv; p.ff_keys_w = ff_keys_w;
        p.ff_keys_b = ff_keys_b; p.res_wq = res_wq; p.res_wkv = res_wkv;
        p.res_wo = res_wo; p.attn_wo = attn_wo; p.ff_values_w = ff_values_w;
        p.ff_values_b = ff_values_b;
        p.attn_norm_w = attn_norm_w; p.ff_norm_w = ff_norm_w; p.res_norm_w = res_norm_w;
        p.tok_in = tok_in;
        p.wqb = wqb; p.wkvb = wkvb; p.fkb = fkb; p.rqb = rqb; p.rkvb = rkvb;
        p.rob = rob; p.woTb = woTb; p.fvwTb = fvwTb; p.tokbf = tokbf;
        p.biasWf = biasWf; p.biasFK = biasFK; p.ssq = ssq;
        setup_all<<<SETUP_BLOCKS, 256, 0, stream>>>(p);
    }

    auto mk = [](const h16* A, long Apl, int lda,
                 const h16* W, long Wpl, int ldw,
                 const float* bias, const float* rss, float* ssqn,
                 float* C, int ldc, int Nd,
                 h16* Cbf, long bfpl, int mbase, int K,
                 int mode, int nbx) -> GDesc {
        GDesc d;
        d.A = A; d.Apl = Apl; d.lda = lda;
        d.W = W; d.Wpl = Wpl; d.ldw = ldw;
        d.bias = bias; d.rss = rss; d.ssqn = ssqn;
        d.C = C; d.ldc = ldc; d.Nd = Nd;
        d.Cbf = Cbf; d.bfpl = bfpl; d.mbase = mbase; d.K = K;
        d.mode = mode; d.nbx = nbx;
        return d;
    };

    // ---- fold batch: Wf(352) + Wa(128) + constant e0 token-KV(256) ----
    {
        GDesc dWf = mk(rkvb, w2, 512, fvwTb, w5, 512, nullptr, nullptr, nullptr,
                       nullptr, KFF, KFF, Wfb, wf_pl, 0, 512, 1, 16);
        GDesc dWa = mk(rkvb, w2, 512, woTb, w1, 512, nullptr, nullptr, nullptr,
                       nullptr, 512, 512, Wab, wa_pl, 0, 512, 1, 16);
        GDesc dtokKV = mk(tokbf, apl, 512, rkvb, w2, 512, nullptr, nullptr, nullptr,
                          kvc3, 1024, 1024, nullptr, 0, 0, 512, 3, 16);
        mega_gemm<64, 64><<<736, 256, 0, stream>>>(dWf, dWa, dtokKV, dtokKV, 352, 480, 736);
    }

    for (int e = 0; e < 3; ++e) {
        float* rse = ssq + (long)e * 1024;
        // ---- B1: ffk+GLU(688) + wkv K/V^T(256) + wq(128) + rq(128) = 1200 ----
        {
            GDesc dffk = mk(tokbf, apl, 512, fkb,  w3, 512, biasFK, rse, nullptr,
                            nullptr, KFF, DFF2, hbf, hpl, 0, 512, 6, 16);
            GDesc dwkv = mk(tokbf, apl, 512, wkvb, w2, 512, nullptr, nullptr, nullptr,
                            (float*)vtb, 1024, 1024, khl, apl, 0, 512, 4, 16);
            GDesc dwq  = mk(tokbf, apl, 512, wqb,  w1, 512, nullptr, rse, nullptr,
                            nullptr, 512, 512, qhl, apl, 0, 512, 1, 16);
            GDesc drq  = mk(tokbf, apl, 512, rqb,  w1, 512, nullptr, rse, nullptr,
                            qbuf, 512, 512, nullptr, 0, 0, 512, 0, 16);
            mega_gemm<64, 64><<<1200, 256, 0, stream>>>(dffk, dwkv, dwq, drq, 688, 944, 1072);
        }
        // ---- fused: self-attention (128) + ffv-kv GEMM (256) ----
        {
            GDesc dffvKV = mk(hbf, hpl, KFF, Wfb, wf_pl, KFF, biasWf, nullptr, nullptr,
                              kvc3, 1024, 1024, nullptr, 0, 2 + 2 * e, KFF, 3, 16);
            attn_ffv<<<384, 256, 0, stream>>>(dffvKV, qhl, khl, vtb, apl, abf);
        }
        // ---- woKV (256) ----
        {
            GDesc dwoKV = mk(abf, apl, 512, Wab, wa_pl, 512, nullptr, nullptr, nullptr,
                             kvc3, 1024, 1024, nullptr, 0, 1 + 2 * e, 512, 3, 16);
            mega_gemm<64, 64><<<256, 256, 0, stream>>>(dwoKV, dwoKV, dwoKV, dwoKV, 256, 256, 256);
        }
        // ---- pooled attention ----
        if (e == 0)      attn_pool_kernel<6><<<512 * NH, 128, 0, stream>>>(qbuf, kvc3, abf, apl);
        else if (e == 1) attn_pool_kernel<10><<<512 * NH, 128, 0, stream>>>(qbuf, kvc3, abf, apl);
        else             attn_pool_kernel<14><<<512 * NH, 128, 0, stream>>>(qbuf, kvc3, abf, apl);
        // ---- ro (BM=32, BN=128, 128 blocks): fp16 out + ssq accumulate ----
        {
            if (e < 2) {
                GDesc dro = mk(abf, apl, 512, rob, w1, 512, nullptr, nullptr,
                               ssq + (long)(e + 1) * 1024,
                               nullptr, 512, 512, tokbf, apl, 0, 512, 1, 32);
                mega_gemm<32, 128><<<128, 256, 0, stream>>>(dro, dro, dro, dro, 128, 128, 128);
            } else {
                GDesc dro = mk(abf, apl, 512, rob, w1, 512, nullptr, nullptr, nullptr,
                               (float*)d_out, 512, 512, nullptr, 0, 0, 512, 5, 32);
                mega_gemm<32, 128><<<128, 256, 0, stream>>>(dro, dro, dro, dro, 128, 128, 128);
            }
        }
    }
}